// Round 1
// baseline (282.856 us; speedup 1.0000x reference)
//
#include <hip/hip_runtime.h>

// Problem constants (match reference)
#define NCOMP 8
#define NCONT 56
#define NCAT 8
#define NU 100
#define NROWS 32768
#define SEPC 1e-3f
#define T1F 10.0f

// LDS layouts:
//  sWh/sWv: [i][c*16+k], row stride 132 floats (pad +4) -> ds_read_b128 bank
//  group = (i + const) % 8, 7 lanes/group -> conflict-free b128.
//  sWic:   [i][k], stride 20 floats -> also conflict-free for b128.
#define WST 132
#define WICST 20

__device__ __forceinline__ float sp(float x) {
    // stable softplus: max(x,0) + log1p(exp(-|x|)); fast intrinsics are fine
    // (validation threshold is ~1e-3 relative of output magnitude)
    return fmaxf(x, 0.0f) + __logf(1.0f + __expf(-fabsf(x)));
}

__device__ __forceinline__ float dot4(float4 a, float4 b) {
    return fmaf(a.x, b.x, fmaf(a.y, b.y, fmaf(a.z, b.z, a.w * b.w)));
}

__global__ __launch_bounds__(1024) void tpm_kernel(
    const float* __restrict__ B, const float* __restrict__ Bcat,
    const float* __restrict__ Wh, const float* __restrict__ Whc, const float* __restrict__ bh,
    const float* __restrict__ Wv, const float* __restrict__ Wvc, const float* __restrict__ bv,
    const float* __restrict__ Wic, const float* __restrict__ Wicc, const float* __restrict__ bic,
    float* __restrict__ out)
{
    __shared__ float sWh[NCONT * WST];    // 29568 B
    __shared__ float sWv[NCONT * WST];    // 29568 B
    __shared__ float sWic[NCONT * WICST]; // 4480 B
    __shared__ int   sCode[16][NCAT];     // per-wave one-hot codes, 512 B

    const int tid = threadIdx.x;

    // Cooperative weight staging: Wh (k,i,c) -> sWh[i][c*16+k]
    for (int idx = tid; idx < NCONT * 128; idx += 1024) {
        int i = idx >> 7, rem = idx & 127;
        int c = rem >> 4, k = rem & 15;
        sWh[i * WST + rem] = Wh[(k * NCONT + i) * NCOMP + c];
        sWv[i * WST + rem] = Wv[(k * NCONT + i) * NCOMP + c];
    }
    for (int idx = tid; idx < NCONT * 16; idx += 1024) {
        int i = idx >> 4, k = idx & 15;
        sWic[i * WICST + k] = Wic[k * NCONT + i];
    }
    __syncthreads();

    const int lane = tid & 63;
    const int widx = tid >> 6;
    const int gw = (blockIdx.x << 4) + widx;   // global wave id
    const int nw = gridDim.x << 4;

    // softplus'd biases, computed once per thread (constant across rows)
    float bhs[NCOMP], bvs[NCOMP];
#pragma unroll
    for (int c = 0; c < NCOMP; ++c) { bhs[c] = sp(bh[c]); bvs[c] = sp(bv[c]); }
    const float bic0 = bic[0];

    for (int r = gw; r < NROWS; r += nw) {
        // ---- phase 1: full-wave coalesced scan of one-hot B_cat row ----
        const float4* pc = (const float4*)(Bcat + (size_t)r * 800);
#pragma unroll
        for (int it = 0; it < 4; ++it) {
            int v = it * 64 + lane;
            if (v < 200) {
                float4 q = pc[v];
                int n = v * 4;
                // 100 % 4 == 0 -> a float4 never straddles a category block
                if (q.x > 0.5f) sCode[widx][(n + 0) / NU] = (n + 0) % NU;
                if (q.y > 0.5f) sCode[widx][(n + 1) / NU] = (n + 1) % NU;
                if (q.z > 0.5f) sCode[widx][(n + 2) / NU] = (n + 2) % NU;
                if (q.w > 0.5f) sCode[widx][(n + 3) / NU] = (n + 3) % NU;
            }
        }
        __threadfence_block();  // make sCode writes visible within the wave

        // ---- phase 2: per-feature raw GAM values ----
        float h[NCOMP], w[NCOMP], ic;
        if (lane < NCONT) {
            // continuous feature `lane`
            const float4* pB = (const float4*)(B + (size_t)r * 896 + lane * 16);
            float4 b0 = pB[0], b1 = pB[1], b2 = pB[2], b3 = pB[3];
            const float4* ph = (const float4*)(&sWh[lane * WST]);
            const float4* pv = (const float4*)(&sWv[lane * WST]);
#pragma unroll
            for (int c = 0; c < NCOMP; ++c) {
                h[c] = dot4(b0, ph[c * 4 + 0]) + dot4(b1, ph[c * 4 + 1]) +
                       dot4(b2, ph[c * 4 + 2]) + dot4(b3, ph[c * 4 + 3]);
                w[c] = dot4(b0, pv[c * 4 + 0]) + dot4(b1, pv[c * 4 + 1]) +
                       dot4(b2, pv[c * 4 + 2]) + dot4(b3, pv[c * 4 + 3]);
            }
            const float4* pi = (const float4*)(&sWic[lane * WICST]);
            ic = dot4(b0, pi[0]) + dot4(b1, pi[1]) + dot4(b2, pi[2]) + dot4(b3, pi[3]);
        } else {
            // categorical feature f = lane - 56: gather weight row (L2-hot, 25 KB tables)
            int f = lane - NCONT;
            int g = f * NU + sCode[widx][f];
            const float4* qh = (const float4*)(Whc + g * 8);
            const float4* qv = (const float4*)(Wvc + g * 8);
            float4 a0 = qh[0], a1 = qh[1];
            float4 c0 = qv[0], c1 = qv[1];
            h[0] = a0.x; h[1] = a0.y; h[2] = a0.z; h[3] = a0.w;
            h[4] = a1.x; h[5] = a1.y; h[6] = a1.z; h[7] = a1.w;
            w[0] = c0.x; w[1] = c0.y; w[2] = c0.z; w[3] = c0.w;
            w[4] = c1.x; w[5] = c1.y; w[6] = c1.z; w[7] = c1.w;
            ic = Wicc[g];
        }

        // softplus on H and V contributions (IC stays raw)
#pragma unroll
        for (int c = 0; c < NCOMP; ++c) { h[c] = sp(h[c]); w[c] = sp(w[c]); }

        // ---- phase 3: butterfly reduction of 17 sums across 64 lanes ----
#pragma unroll
        for (int off = 32; off >= 1; off >>= 1) {
#pragma unroll
            for (int c = 0; c < NCOMP; ++c) {
                h[c] += __shfl_xor(h[c], off, 64);
                w[c] += __shfl_xor(w[c], off, 64);
            }
            ic += __shfl_xor(ic, off, 64);
        }
#pragma unroll
        for (int c = 0; c < NCOMP; ++c) { h[c] += bhs[c]; w[c] += bvs[c]; }
        ic += bic0;

        // ---- phase 4: lanes 0..8 each produce one (t, x) pair ----
        if (lane < 9) {
            int m = (lane == 8) ? 7 : lane;   // t[8] = max(t[7]+SEP, T1)
            float tj = SEPC * (float)lane;    // T0 = 0
            float xj = ic;                    // x0 = IC.sum()
#pragma unroll
            for (int c = 0; c < NCOMP; ++c) {
                if (c < m)    tj += h[c];
                if (c < lane) xj += (c & 1) ? -w[c] : w[c];  // SIGNS = +,-,+,-,...
            }
            if (lane == 8) tj = fmaxf(tj, T1F);
            float2 o; o.x = tj; o.y = xj;
            ((float2*)(out + (size_t)r * 18))[lane] = o;   // coalesced 72 B/row
        }
    }
}

extern "C" void kernel_launch(void* const* d_in, const int* in_sizes, int n_in,
                              void* d_out, int out_size, void* d_ws, size_t ws_size,
                              hipStream_t stream) {
    (void)in_sizes; (void)n_in; (void)out_size; (void)d_ws; (void)ws_size;
    const float* B    = (const float*)d_in[0];
    const float* Bcat = (const float*)d_in[1];
    const float* Wh   = (const float*)d_in[2];
    const float* Whc  = (const float*)d_in[3];
    const float* bh   = (const float*)d_in[4];
    const float* Wv   = (const float*)d_in[5];
    const float* Wvc  = (const float*)d_in[6];
    const float* bv   = (const float*)d_in[7];
    const float* Wic  = (const float*)d_in[8];
    const float* Wicc = (const float*)d_in[9];
    const float* bic  = (const float*)d_in[10];
    float* out = (float*)d_out;

    // 256 blocks x 16 waves = 4096 waves -> 8 rows per wave; 1 block/CU, 64KB LDS
    hipLaunchKernelGGL(tpm_kernel, dim3(256), dim3(1024), 0, stream,
                       B, Bcat, Wh, Whc, bh, Wv, Wvc, bv, Wic, Wicc, bic, out);
}

// Round 4
// 274.950 us; speedup vs baseline: 1.0288x; 1.0288x over previous
//
#include <hip/hip_runtime.h>

#define NCOMP 8
#define NCONT 56
#define NCAT 8
#define NU 100
#define NROWS 32768
#define SEPC 1e-3f
#define T1F 10.0f

// native type of __builtin_amdgcn_cvt_pkrtz / __builtin_amdgcn_fdot2 operands
typedef __fp16 f16x2 __attribute__((ext_vector_type(2)));
// arithmetic-friendly fp16 pair for the packed butterfly add
typedef _Float16 h2arith __attribute__((ext_vector_type(2)));

// LDS: per feature i, 16 chunks of 16B (8 f16 each) at stride 17 chunks (+1 pad).
#define HSTRIDE 17
#define ICSTRIDE 3

union H8 { f16x2 h2[4]; float4 f4; };

__device__ __forceinline__ float sp(float x) {
    // softplus = ln2 * log2(1 + 2^(x*log2e)) via v_exp_f32/v_log_f32
    return 0.69314718f * __builtin_amdgcn_logf(1.0f + __builtin_amdgcn_exp2f(x * 1.44269504f));
}

__device__ __forceinline__ f16x2 pkrtz(float a, float b) {
    return __builtin_amdgcn_cvt_pkrtz(a, b);
}

__device__ __forceinline__ float fdot2(f16x2 a, f16x2 b, float c) {
    return __builtin_amdgcn_fdot2(a, b, c, false);
}

__device__ __forceinline__ h2arith h2shfl_xor(h2arith v, int off) {
    int i = __builtin_bit_cast(int, v);
    i = __shfl_xor(i, off, 64);
    return __builtin_bit_cast(h2arith, i);
}

__global__ __launch_bounds__(1024, 8) void tpm_kernel(
    const float* __restrict__ B, const float* __restrict__ Bcat,
    const float* __restrict__ Wh, const float* __restrict__ Whc, const float* __restrict__ bh,
    const float* __restrict__ Wv, const float* __restrict__ Wvc, const float* __restrict__ bv,
    const float* __restrict__ Wic, const float* __restrict__ Wicc, const float* __restrict__ bic,
    float* __restrict__ out)
{
    __shared__ float4 sH4[NCONT * HSTRIDE];   // 15232 B, f16 weights Wh
    __shared__ float4 sV4[NCONT * HSTRIDE];   // 15232 B, f16 weights Wv
    __shared__ float4 sIC4[NCONT * ICSTRIDE]; // 2688 B,  f16 weights Wic
    __shared__ float2 sBias[NCOMP];           // (sp(bh), sp(bv))
    __shared__ float  sBic;
    __shared__ int    sCode[16][NCAT];        // per-wave one-hot codes

    const int tid = threadIdx.x;

    // ---- stage Wh/Wv as f16, coalesced: idx -> (icp = i*8+c, t), addr k*448+icp ----
    if (tid < 896) {
        int icp = tid % 448, t = tid / 448;
        int i = icp >> 3, c = icp & 7;
        const float* gh = Wh + (size_t)(8 * t) * 448 + icp;
        const float* gv = Wv + (size_t)(8 * t) * 448 + icp;
        H8 uh, uv;
#pragma unroll
        for (int p = 0; p < 4; ++p) {
            uh.h2[p] = pkrtz(gh[(2 * p) * 448], gh[(2 * p + 1) * 448]);
            uv.h2[p] = pkrtz(gv[(2 * p) * 448], gv[(2 * p + 1) * 448]);
        }
        sH4[i * HSTRIDE + c * 2 + t] = uh.f4;
        sV4[i * HSTRIDE + c * 2 + t] = uv.f4;
    }
    if (tid < 112) {
        int i = tid % 56, t = tid / 56;
        const float* gi = Wic + (size_t)(8 * t) * 56 + i;
        H8 u;
#pragma unroll
        for (int p = 0; p < 4; ++p)
            u.h2[p] = pkrtz(gi[(2 * p) * 56], gi[(2 * p + 1) * 56]);
        sIC4[i * ICSTRIDE + t] = u.f4;
    }
    if (tid < NCOMP) sBias[tid] = make_float2(sp(bh[tid]), sp(bv[tid]));
    if (tid == NCOMP) sBic = bic[0];
    __syncthreads();

    const int lane = tid & 63;
    const int widx = tid >> 6;
    const int gw = (blockIdx.x << 4) + widx;
    const int nw = gridDim.x << 4;

    // lane-constant LDS base pointers (hoisted out of the row loop)
    const float4* pH = sH4 + lane * HSTRIDE;
    const float4* pV = sV4 + lane * HSTRIDE;
    const float4* pIC = sIC4 + lane * ICSTRIDE;

    for (int r = gw; r < NROWS; r += nw) {
        // ---- one-hot scan: s = dot(q, n+1..n+4) is exact (q in {0,1}) ----
        const float4* pc = (const float4*)(Bcat + (size_t)r * 800);
#pragma unroll
        for (int it = 0; it < 4; ++it) {
            int v = it * 64 + lane;
            if (it < 3 || v < 200) {
                float4 q = pc[v];
                float n = (float)(4 * v);
                float s = q.x * (n + 1.0f) + q.y * (n + 2.0f) + q.z * (n + 3.0f) + q.w * (n + 4.0f);
                if (s > 0.5f) {
                    int p = (int)s - 1;
                    int f = p / NU;
                    sCode[widx][f] = p - f * NU;
                }
            }
        }
        __threadfence_block();

        float h[NCOMP], w[NCOMP], ic;
        if (lane < NCONT) {
            const float4* pB = (const float4*)(B + (size_t)r * 896 + lane * 16);
            float4 b0 = pB[0], b1 = pB[1], b2 = pB[2], b3 = pB[3];
            f16x2 bb[8];
            bb[0] = pkrtz(b0.x, b0.y);
            bb[1] = pkrtz(b0.z, b0.w);
            bb[2] = pkrtz(b1.x, b1.y);
            bb[3] = pkrtz(b1.z, b1.w);
            bb[4] = pkrtz(b2.x, b2.y);
            bb[5] = pkrtz(b2.z, b2.w);
            bb[6] = pkrtz(b3.x, b3.y);
            bb[7] = pkrtz(b3.z, b3.w);
#pragma unroll
            for (int c = 0; c < NCOMP; ++c) {
                H8 u0, u1, v0, v1;
                u0.f4 = pH[2 * c]; u1.f4 = pH[2 * c + 1];
                v0.f4 = pV[2 * c]; v1.f4 = pV[2 * c + 1];
                float ah = 0.0f, av = 0.0f;
#pragma unroll
                for (int p = 0; p < 4; ++p) {
                    ah = fdot2(bb[p], u0.h2[p], ah);
                    av = fdot2(bb[p], v0.h2[p], av);
                }
#pragma unroll
                for (int p = 0; p < 4; ++p) {
                    ah = fdot2(bb[4 + p], u1.h2[p], ah);
                    av = fdot2(bb[4 + p], v1.h2[p], av);
                }
                h[c] = ah; w[c] = av;
            }
            H8 i0, i1;
            i0.f4 = pIC[0]; i1.f4 = pIC[1];
            float ai = 0.0f;
#pragma unroll
            for (int p = 0; p < 4; ++p) ai = fdot2(bb[p], i0.h2[p], ai);
#pragma unroll
            for (int p = 0; p < 4; ++p) ai = fdot2(bb[4 + p], i1.h2[p], ai);
            ic = ai;
        } else {
            int f = lane - NCONT;
            int g = f * NU + sCode[widx][f];
            const float4* qh = (const float4*)(Whc + g * 8);
            const float4* qv = (const float4*)(Wvc + g * 8);
            float4 a0 = qh[0], a1 = qh[1];
            float4 c0 = qv[0], c1 = qv[1];
            h[0] = a0.x; h[1] = a0.y; h[2] = a0.z; h[3] = a0.w;
            h[4] = a1.x; h[5] = a1.y; h[6] = a1.z; h[7] = a1.w;
            w[0] = c0.x; w[1] = c0.y; w[2] = c0.z; w[3] = c0.w;
            w[4] = c1.x; w[5] = c1.y; w[6] = c1.z; w[7] = c1.w;
            ic = Wicc[g];
        }

        // softplus H,V; pack (h,w) into f16 pairs for a 9-value butterfly
        h2arith hw[NCOMP];
#pragma unroll
        for (int c = 0; c < NCOMP; ++c)
            hw[c] = __builtin_bit_cast(h2arith, pkrtz(sp(h[c]), sp(w[c])));

#pragma unroll
        for (int off = 32; off >= 1; off >>= 1) {
#pragma unroll
            for (int c = 0; c < NCOMP; ++c)
                hw[c] = hw[c] + h2shfl_xor(hw[c], off);   // v_pk_add_f16
            ic += __shfl_xor(ic, off, 64);
        }

        // ---- lanes 0..8 emit (t, x) ----
        if (lane < 9) {
            int m = (lane == 8) ? 7 : lane;
            float tj = SEPC * (float)lane;
            float xj = ic + sBic;
#pragma unroll
            for (int c = 0; c < NCOMP; ++c) {
                float2 bb2 = sBias[c];
                if (c < m)    tj += (float)hw[c][0] + bb2.x;
                if (c < lane) {
                    float vv = (float)hw[c][1] + bb2.y;
                    xj += (c & 1) ? -vv : vv;
                }
            }
            if (lane == 8) tj = fmaxf(tj, T1F);
            float2 o; o.x = tj; o.y = xj;
            ((float2*)out)[(size_t)r * 9 + lane] = o;
        }
    }
}

extern "C" void kernel_launch(void* const* d_in, const int* in_sizes, int n_in,
                              void* d_out, int out_size, void* d_ws, size_t ws_size,
                              hipStream_t stream) {
    (void)in_sizes; (void)n_in; (void)out_size; (void)d_ws; (void)ws_size;
    const float* B    = (const float*)d_in[0];
    const float* Bcat = (const float*)d_in[1];
    const float* Wh   = (const float*)d_in[2];
    const float* Whc  = (const float*)d_in[3];
    const float* bh   = (const float*)d_in[4];
    const float* Wv   = (const float*)d_in[5];
    const float* Wvc  = (const float*)d_in[6];
    const float* bv   = (const float*)d_in[7];
    const float* Wic  = (const float*)d_in[8];
    const float* Wicc = (const float*)d_in[9];
    const float* bic  = (const float*)d_in[10];
    float* out = (float*)d_out;

    // 512 blocks x 16 waves: 2 blocks/CU (~33 KB LDS), 32 waves/CU; 4 rows/wave
    hipLaunchKernelGGL(tpm_kernel, dim3(512), dim3(1024), 0, stream,
                       B, Bcat, Wh, Whc, bh, Wv, Wvc, bv, Wic, Wicc, bic, out);
}

// Round 5
// 262.970 us; speedup vs baseline: 1.0756x; 1.0456x over previous
//
#include <hip/hip_runtime.h>

#define NCOMP 8
#define NCONT 56
#define NCAT 8
#define NU 100
#define NROWS 32768
#define SEPC 1e-3f
#define T1F 10.0f

// native type of __builtin_amdgcn_cvt_pkrtz / __builtin_amdgcn_fdot2 operands
typedef __fp16 f16x2 __attribute__((ext_vector_type(2)));
// arithmetic-friendly fp16 pair for the packed butterfly add
typedef _Float16 h2arith __attribute__((ext_vector_type(2)));

// One combined weight array: per feature f (0..55), 35 float4 "roles":
//  role 2c+t      : Wh comp c, k=8t..8t+7   (16 roles)
//  role 16+2c+t   : Wv comp c, k=8t..8t+7   (16 roles)
//  role 32+t      : Wic,       k=8t..8t+7   (2 roles)
//  role 34        : pad
// Feature stride 35*16B = 140 dwords -> sublane bank clusters 12s mod 32:
// 8 distinct clusters, s and s+8 alias (2-way = free).
#define FSTRIDE 35

union H8 { f16x2 h2[4]; float4 f4; };

__device__ __forceinline__ float sp(float x) {
    // softplus = ln2 * log2(1 + 2^(x*log2e)) via v_exp_f32/v_log_f32
    return 0.69314718f * __builtin_amdgcn_logf(1.0f + __builtin_amdgcn_exp2f(x * 1.44269504f));
}

__device__ __forceinline__ f16x2 pkrtz(float a, float b) {
    return __builtin_amdgcn_cvt_pkrtz(a, b);
}

__device__ __forceinline__ float fdot2(f16x2 a, f16x2 b, float c) {
    return __builtin_amdgcn_fdot2(a, b, c, false);
}

__device__ __forceinline__ h2arith h2shfl_xor(h2arith v, int off) {
    int i = __builtin_bit_cast(int, v);
    i = __shfl_xor(i, off, 64);
    return __builtin_bit_cast(h2arith, i);
}

__global__ __launch_bounds__(1024, 4) void tpm_kernel(
    const float* __restrict__ B, const float* __restrict__ Bcat,
    const float* __restrict__ Wh, const float* __restrict__ Whc, const float* __restrict__ bh,
    const float* __restrict__ Wv, const float* __restrict__ Wvc, const float* __restrict__ bv,
    const float* __restrict__ Wic, const float* __restrict__ Wicc, const float* __restrict__ bic,
    float* __restrict__ out)
{
    __shared__ float4 sW[NCONT * FSTRIDE];  // 31360 B, f16 weights (H|V|IC)
    __shared__ float2 sBias[NCOMP];         // (sp(bh), sp(bv))
    __shared__ float  sBic;
    __shared__ int    sCode[16][8][NCAT];   // [wave][local row][cat feature]

    const int tid = threadIdx.x;

    // ---- stage Wh/Wv as f16: tid<896 handles (icp = i*8+c, t) ----
    if (tid < 896) {
        int icp = tid % 448, t = tid / 448;
        int i = icp >> 3, c = icp & 7;
        const float* gh = Wh + (size_t)(8 * t) * 448 + icp;
        const float* gv = Wv + (size_t)(8 * t) * 448 + icp;
        H8 uh, uv;
#pragma unroll
        for (int p = 0; p < 4; ++p) {
            uh.h2[p] = pkrtz(gh[(2 * p) * 448], gh[(2 * p + 1) * 448]);
            uv.h2[p] = pkrtz(gv[(2 * p) * 448], gv[(2 * p + 1) * 448]);
        }
        sW[i * FSTRIDE + 2 * c + t] = uh.f4;
        sW[i * FSTRIDE + 16 + 2 * c + t] = uv.f4;
    }
    if (tid < 112) {
        int i = tid % 56, t = tid / 56;
        const float* gi = Wic + (size_t)(8 * t) * 56 + i;
        H8 u;
#pragma unroll
        for (int p = 0; p < 4; ++p)
            u.h2[p] = pkrtz(gi[(2 * p) * 56], gi[(2 * p + 1) * 56]);
        sW[i * FSTRIDE + 32 + t] = u.f4;
    }
    if (tid < NCOMP) sBias[tid] = make_float2(sp(bh[tid]), sp(bv[tid]));
    if (tid == NCOMP) sBic = bic[0];
    __syncthreads();

    const int lane = tid & 63;
    const int widx = tid >> 6;
    const int s = lane & 15;        // sublane: feature group
    const int g = lane >> 4;        // row group 0..3
    const int R0 = ((blockIdx.x << 4) + widx) << 3;   // 8 rows per wave, exact cover
    const int rA = R0 + g;          // this group's first row
    const int rB = R0 + 4 + g;      // this group's second row

    // ---- full-wave cooperative one-hot scan of 8 rows ----
    {
        const float4* pc = (const float4*)(Bcat + (size_t)R0 * 800);
#pragma unroll
        for (int it = 0; it < 25; ++it) {
            int idx = it * 64 + lane;           // 0..1599
            int row = idx / 200;
            int pos = idx - row * 200;          // float4 within row
            float4 q = pc[row * 200 + pos];
            float n = (float)(4 * pos);
            float sc = q.x * (n + 1.0f) + q.y * (n + 2.0f) + q.z * (n + 3.0f) + q.w * (n + 4.0f);
            if (sc > 0.5f) {
                int p = (int)sc - 1;            // element within row's 800
                int f = p / NU;
                sCode[widx][row][f] = p - f * NU;
            }
        }
    }
    __threadfence_block();

    // ---- accumulators: 17 channels x 2 rows ----
    float shA[NCOMP], swA[NCOMP], shB[NCOMP], swB[NCOMP];
    float icA = 0.0f, icB = 0.0f;
#pragma unroll
    for (int c = 0; c < NCOMP; ++c) { shA[c] = swA[c] = shB[c] = swB[c] = 0.0f; }

    // ---- 4 passes: lane handles features s, s+16, s+32, s+48 ----
#pragma unroll 1
    for (int j = 0; j < 4; ++j) {
        int f = s + 16 * j;
        if (f < NCONT) {
            // continuous feature: basis for 2 rows, dots against LDS weights
            const float4* pA = (const float4*)(B + (size_t)rA * 896 + f * 16);
            const float4* pB = (const float4*)(B + (size_t)rB * 896 + f * 16);
            float4 a0 = pA[0], a1 = pA[1], a2 = pA[2], a3 = pA[3];
            float4 b0 = pB[0], b1 = pB[1], b2 = pB[2], b3 = pB[3];
            f16x2 baA[8], baB[8];
            baA[0] = pkrtz(a0.x, a0.y); baA[1] = pkrtz(a0.z, a0.w);
            baA[2] = pkrtz(a1.x, a1.y); baA[3] = pkrtz(a1.z, a1.w);
            baA[4] = pkrtz(a2.x, a2.y); baA[5] = pkrtz(a2.z, a2.w);
            baA[6] = pkrtz(a3.x, a3.y); baA[7] = pkrtz(a3.z, a3.w);
            baB[0] = pkrtz(b0.x, b0.y); baB[1] = pkrtz(b0.z, b0.w);
            baB[2] = pkrtz(b1.x, b1.y); baB[3] = pkrtz(b1.z, b1.w);
            baB[4] = pkrtz(b2.x, b2.y); baB[5] = pkrtz(b2.z, b2.w);
            baB[6] = pkrtz(b3.x, b3.y); baB[7] = pkrtz(b3.z, b3.w);

            const float4* pw = sW + f * FSTRIDE;
#pragma unroll
            for (int c = 0; c < NCOMP; ++c) {
                H8 u0, u1, v0, v1;
                u0.f4 = pw[2 * c];      u1.f4 = pw[2 * c + 1];
                v0.f4 = pw[16 + 2 * c]; v1.f4 = pw[17 + 2 * c];
                float hA = 0.0f, hB = 0.0f, vA = 0.0f, vB = 0.0f;
#pragma unroll
                for (int p = 0; p < 4; ++p) {
                    hA = fdot2(baA[p], u0.h2[p], hA);
                    hB = fdot2(baB[p], u0.h2[p], hB);
                    vA = fdot2(baA[p], v0.h2[p], vA);
                    vB = fdot2(baB[p], v0.h2[p], vB);
                }
#pragma unroll
                for (int p = 0; p < 4; ++p) {
                    hA = fdot2(baA[4 + p], u1.h2[p], hA);
                    hB = fdot2(baB[4 + p], u1.h2[p], hB);
                    vA = fdot2(baA[4 + p], v1.h2[p], vA);
                    vB = fdot2(baB[4 + p], v1.h2[p], vB);
                }
                shA[c] += sp(hA); shB[c] += sp(hB);
                swA[c] += sp(vA); swB[c] += sp(vB);
            }
            {
                H8 i0, i1;
                i0.f4 = pw[32]; i1.f4 = pw[33];
                float iA = 0.0f, iB = 0.0f;
#pragma unroll
                for (int p = 0; p < 4; ++p) {
                    iA = fdot2(baA[p], i0.h2[p], iA);
                    iB = fdot2(baB[p], i0.h2[p], iB);
                }
#pragma unroll
                for (int p = 0; p < 4; ++p) {
                    iA = fdot2(baA[4 + p], i1.h2[p], iA);
                    iB = fdot2(baB[4 + p], i1.h2[p], iB);
                }
                icA += iA; icB += iB;   // IC has no softplus
            }
        } else {
            // categorical feature (pass 3, sublanes 8..15): f-56 = s-8
            int fi = s - 8;
            int cA = sCode[widx][g][fi];
            int cB = sCode[widx][4 + g][fi];
            int gA = fi * NU + cA;
            int gB = fi * NU + cB;
            const float4* qhA = (const float4*)(Whc + gA * 8);
            const float4* qvA = (const float4*)(Wvc + gA * 8);
            const float4* qhB = (const float4*)(Whc + gB * 8);
            const float4* qvB = (const float4*)(Wvc + gB * 8);
            float4 h0 = qhA[0], h1 = qhA[1], v0 = qvA[0], v1 = qvA[1];
            shA[0] += sp(h0.x); shA[1] += sp(h0.y); shA[2] += sp(h0.z); shA[3] += sp(h0.w);
            shA[4] += sp(h1.x); shA[5] += sp(h1.y); shA[6] += sp(h1.z); shA[7] += sp(h1.w);
            swA[0] += sp(v0.x); swA[1] += sp(v0.y); swA[2] += sp(v0.z); swA[3] += sp(v0.w);
            swA[4] += sp(v1.x); swA[5] += sp(v1.y); swA[6] += sp(v1.z); swA[7] += sp(v1.w);
            icA += Wicc[gA];
            float4 h2 = qhB[0], h3 = qhB[1], v2 = qvB[0], v3 = qvB[1];
            shB[0] += sp(h2.x); shB[1] += sp(h2.y); shB[2] += sp(h2.z); shB[3] += sp(h2.w);
            shB[4] += sp(h3.x); shB[5] += sp(h3.y); shB[6] += sp(h3.z); shB[7] += sp(h3.w);
            swB[0] += sp(v2.x); swB[1] += sp(v2.y); swB[2] += sp(v2.z); swB[3] += sp(v2.w);
            swB[4] += sp(v3.x); swB[5] += sp(v3.y); swB[6] += sp(v3.z); swB[7] += sp(v3.w);
            icB += Wicc[gB];
        }
    }

    // ---- pack and 4-step butterfly within each 16-lane group ----
    h2arith hwA[NCOMP], hwB[NCOMP];
#pragma unroll
    for (int c = 0; c < NCOMP; ++c) {
        hwA[c] = __builtin_bit_cast(h2arith, pkrtz(shA[c], swA[c]));
        hwB[c] = __builtin_bit_cast(h2arith, pkrtz(shB[c], swB[c]));
    }
#pragma unroll
    for (int off = 8; off >= 1; off >>= 1) {
#pragma unroll
        for (int c = 0; c < NCOMP; ++c) {
            hwA[c] = hwA[c] + h2shfl_xor(hwA[c], off);
            hwB[c] = hwB[c] + h2shfl_xor(hwB[c], off);
        }
        icA += __shfl_xor(icA, off, 64);
        icB += __shfl_xor(icB, off, 64);
    }

    // ---- sublanes 0..8 emit (t, x) for both rows ----
    if (s < 9) {
        int m = (s == 9 - 1) ? 7 : s;
        float tA = SEPC * (float)s, tB = tA;
        float xA = icA + sBic, xB = icB + sBic;
#pragma unroll
        for (int c = 0; c < NCOMP; ++c) {
            float2 bb2 = sBias[c];
            if (c < m) {
                tA += (float)hwA[c][0] + bb2.x;
                tB += (float)hwB[c][0] + bb2.x;
            }
            if (c < s) {
                float vA = (float)hwA[c][1] + bb2.y;
                float vB = (float)hwB[c][1] + bb2.y;
                xA += (c & 1) ? -vA : vA;
                xB += (c & 1) ? -vB : vB;
            }
        }
        if (s == 8) { tA = fmaxf(tA, T1F); tB = fmaxf(tB, T1F); }
        float2 oA; oA.x = tA; oA.y = xA;
        float2 oB; oB.x = tB; oB.y = xB;
        ((float2*)out)[(size_t)rA * 9 + s] = oA;
        ((float2*)out)[(size_t)rB * 9 + s] = oB;
    }
}

extern "C" void kernel_launch(void* const* d_in, const int* in_sizes, int n_in,
                              void* d_out, int out_size, void* d_ws, size_t ws_size,
                              hipStream_t stream) {
    (void)in_sizes; (void)n_in; (void)out_size; (void)d_ws; (void)ws_size;
    const float* B    = (const float*)d_in[0];
    const float* Bcat = (const float*)d_in[1];
    const float* Wh   = (const float*)d_in[2];
    const float* Whc  = (const float*)d_in[3];
    const float* bh   = (const float*)d_in[4];
    const float* Wv   = (const float*)d_in[5];
    const float* Wvc  = (const float*)d_in[6];
    const float* bv   = (const float*)d_in[7];
    const float* Wic  = (const float*)d_in[8];
    const float* Wicc = (const float*)d_in[9];
    const float* bic  = (const float*)d_in[10];
    float* out = (float*)d_out;

    // 256 blocks x 16 waves x 8 rows = 32768 rows, exact cover
    hipLaunchKernelGGL(tpm_kernel, dim3(256), dim3(1024), 0, stream,
                       B, Bcat, Wh, Whc, bh, Wv, Wvc, bv, Wic, Wicc, bic, out);
}